// Round 5
// baseline (607.311 us; speedup 1.0000x reference)
//
#include <hip/hip_runtime.h>
#include <math.h>

#define NEG 0.2f

typedef __bf16 bf16x4 __attribute__((ext_vector_type(4)));
typedef __bf16 bf16x8 __attribute__((ext_vector_type(8)));
typedef float  f32x4  __attribute__((ext_vector_type(4)));

// ---------------------------------------------------------------------------
// K1: h1[N,64] = x[N,512] @ W1[512,64] via bf16 MFMA (16x16x32).
// Block = 64 rows x 64 cols, 4 waves; wave w owns cols [16w,16w+16).
// W1 fragments live in registers (16 chunks x 8 bf16/lane = 64 VGPRs).
// x staged per-chunk into double-buffered bf16 LDS, row stride 40 (pad).
// ---------------------------------------------------------------------------
__global__ __launch_bounds__(256) void gemm1_k(const float* __restrict__ x,
                                               const float* __restrict__ W1,
                                               float* __restrict__ h1, int Nn)
{
    __shared__ __bf16 xs[2][64][40];
    int t = threadIdx.x;
    int wave = t >> 6, lane = t & 63;
    int row0 = blockIdx.x * 64;
    int col0 = wave * 16;
    int lm = lane & 15;   // m (A) / n (B) / col (C)
    int lk = lane >> 4;   // k-group

    // Preload B fragments: B[k][n] with n = col0+lm, k = ch*32 + lk*8 + j
    bf16x8 bfrag[16];
#pragma unroll
    for (int ch = 0; ch < 16; ++ch) {
        int kb = ch * 32 + lk * 8;
#pragma unroll
        for (int j = 0; j < 8; ++j)
            bfrag[ch][j] = (__bf16)W1[(size_t)(kb + j) * 64 + col0 + lm];
    }

    f32x4 acc[4] = {};

    // stage chunk 0 into buffer 0
    {
        int r = t >> 3, c4 = t & 7;
#pragma unroll
        for (int p = 0; p < 2; ++p) {
            int rr = p * 32 + r;
            int gr = row0 + rr;
            float4 v = make_float4(0.f, 0.f, 0.f, 0.f);
            if (gr < Nn) v = *(const float4*)(x + (size_t)gr * 512 + c4 * 4);
            bf16x4 b;
            b[0] = (__bf16)v.x; b[1] = (__bf16)v.y; b[2] = (__bf16)v.z; b[3] = (__bf16)v.w;
            *(bf16x4*)&xs[0][rr][c4 * 4] = b;
        }
    }
    __syncthreads();

#pragma unroll
    for (int ch = 0; ch < 16; ++ch) {
        int buf = ch & 1;
        if (ch < 15) {
            int kb = (ch + 1) * 32;
            int r = t >> 3, c4 = t & 7;
#pragma unroll
            for (int p = 0; p < 2; ++p) {
                int rr = p * 32 + r;
                int gr = row0 + rr;
                float4 v = make_float4(0.f, 0.f, 0.f, 0.f);
                if (gr < Nn) v = *(const float4*)(x + (size_t)gr * 512 + kb + c4 * 4);
                bf16x4 b;
                b[0] = (__bf16)v.x; b[1] = (__bf16)v.y; b[2] = (__bf16)v.z; b[3] = (__bf16)v.w;
                *(bf16x4*)&xs[1 - buf][rr][c4 * 4] = b;
            }
        }
#pragma unroll
        for (int rt = 0; rt < 4; ++rt) {
            bf16x8 a = *(bf16x8*)&xs[buf][rt * 16 + lm][lk * 8];
            acc[rt] = __builtin_amdgcn_mfma_f32_16x16x32_bf16(a, bfrag[ch], acc[rt], 0, 0, 0);
        }
        __syncthreads();
    }

    // C/D layout: col = lane&15, row = lk*4 + reg (verified m89)
#pragma unroll
    for (int rt = 0; rt < 4; ++rt) {
#pragma unroll
        for (int j = 0; j < 4; ++j) {
            int gr = row0 + rt * 16 + lk * 4 + j;
            if (gr < Nn) h1[(size_t)gr * 64 + col0 + lm] = acc[rt][j];
        }
    }
}

// ---------------------------------------------------------------------------
// K2: per-(node,head) attention dots for layer 1
// ---------------------------------------------------------------------------
__global__ void attn1_k(const float* __restrict__ h1, const float* __restrict__ asrc,
                        const float* __restrict__ adst, float* __restrict__ as1,
                        float* __restrict__ ad1, int Nn)
{
    int tid = blockIdx.x * 256 + threadIdx.x;
    if (tid >= Nn * 8) return;
    int n = tid >> 3, h = tid & 7;
    const float* hp = h1 + (size_t)n * 64 + h * 8;
    float s = 0.f, d = 0.f;
#pragma unroll
    for (int c = 0; c < 8; ++c) {
        float v = hp[c];
        s += v * asrc[h * 8 + c];
        d += v * adst[h * 8 + c];
    }
    as1[tid] = s;
    ad1[tid] = d;
}

// ---------------------------------------------------------------------------
// CSR build: fused histogram+rank -> 3-kernel exclusive scan -> atomic-free
// scatter.
// ---------------------------------------------------------------------------
__global__ void hist_rank_k(const int* __restrict__ ei, int E, int Nn,
                            int* __restrict__ deg, int* __restrict__ rank)
{
    int e = blockIdx.x * 256 + threadIdx.x;
    int Ep = E + Nn;
    if (e >= Ep) return;
    int d = (e < E) ? ei[E + e] : e - E;
    rank[e] = atomicAdd(&deg[d], 1);
}

__global__ void scan_a_k(const int* __restrict__ deg, int Nn, int* __restrict__ bsum)
{
    __shared__ int tmp[256];
    int t = threadIdx.x;
    int base = blockIdx.x * 1024 + t * 4;
    int s = 0;
#pragma unroll
    for (int j = 0; j < 4; ++j) { int i = base + j; if (i < Nn) s += deg[i]; }
    tmp[t] = s;
    __syncthreads();
    for (int off = 1; off < 256; off <<= 1) {
        int a = (t >= off) ? tmp[t - off] : 0;
        __syncthreads();
        tmp[t] += a;
        __syncthreads();
    }
    if (t == 255) bsum[blockIdx.x] = tmp[255];
}

__global__ void scan_b_k(int* __restrict__ bsum, int nb)
{
    __shared__ int tmp[256];
    int t = threadIdx.x;
    int v = (t < nb) ? bsum[t] : 0;
    tmp[t] = v;
    __syncthreads();
    for (int off = 1; off < 256; off <<= 1) {
        int a = (t >= off) ? tmp[t - off] : 0;
        __syncthreads();
        tmp[t] += a;
        __syncthreads();
    }
    if (t < nb) bsum[t] = tmp[t] - v;  // exclusive
}

__global__ void scan_c_k(const int* __restrict__ deg, int Nn, const int* __restrict__ boff,
                         int* __restrict__ rowptr)
{
    __shared__ int tmp[256];
    int t = threadIdx.x;
    int base = blockIdx.x * 1024 + t * 4;
    int v[4];
    int s = 0;
#pragma unroll
    for (int j = 0; j < 4; ++j) {
        int i = base + j;
        v[j] = (i < Nn) ? deg[i] : 0;
        s += v[j];
    }
    tmp[t] = s;
    __syncthreads();
    for (int off = 1; off < 256; off <<= 1) {
        int a = (t >= off) ? tmp[t - off] : 0;
        __syncthreads();
        tmp[t] += a;
        __syncthreads();
    }
    int excl = boff[blockIdx.x] + tmp[t] - s;
#pragma unroll
    for (int j = 0; j < 4; ++j) {
        int i = base + j;
        if (i < Nn) {
            rowptr[i] = excl;
            excl += v[j];
            if (i == Nn - 1) rowptr[Nn] = excl;
        }
    }
}

__global__ void scat2_k(const int* __restrict__ ei, int E, int Nn,
                        const int* __restrict__ rowptr, const int* __restrict__ rank,
                        int* __restrict__ csr)
{
    int e = blockIdx.x * 256 + threadIdx.x;
    int Ep = E + Nn;
    if (e >= Ep) return;
    int s, d;
    if (e < E) { s = ei[e]; d = ei[E + e]; } else { s = d = e - E; }
    csr[rowptr[d] + rank[e]] = s;
}

// ---------------------------------------------------------------------------
// Layer-1 fused softmax+aggregate: one wave per dst node.
// lane = sub*16 + c4 (sub = edge slot, c4 = float4 chunk of the 64-ch row).
// 4-deep unroll -> 16 edge gathers in flight per wave.
// ---------------------------------------------------------------------------
__global__ __launch_bounds__(256) void agg1_k(const int* __restrict__ csr,
                                              const int* __restrict__ rowptr,
                                              const float* __restrict__ as1,
                                              const float* __restrict__ ad1,
                                              const float* __restrict__ h1,
                                              float* __restrict__ out1, int Nn)
{
    int wid = (blockIdx.x * 256 + threadIdx.x) >> 6;
    if (wid >= Nn) return;
    int lane = threadIdx.x & 63;
    int sub = lane >> 4;
    int c4 = lane & 15;
    int h = c4 >> 1;
    float adv = ad1[wid * 8 + h];
    int start = rowptr[wid];
    int len = rowptr[wid + 1] - start;
    float accp = 0.f;
    float4 accv = make_float4(0.f, 0.f, 0.f, 0.f);
    int i = sub;
    for (; i + 12 < len; i += 16) {
        int s0 = csr[start + i];
        int s1 = csr[start + i + 4];
        int s2 = csr[start + i + 8];
        int s3 = csr[start + i + 12];
        float e0 = as1[s0 * 8 + h] + adv;
        float e1 = as1[s1 * 8 + h] + adv;
        float e2 = as1[s2 * 8 + h] + adv;
        float e3 = as1[s3 * 8 + h] + adv;
        float4 hv0 = *(const float4*)(h1 + (size_t)s0 * 64 + c4 * 4);
        float4 hv1 = *(const float4*)(h1 + (size_t)s1 * 64 + c4 * 4);
        float4 hv2 = *(const float4*)(h1 + (size_t)s2 * 64 + c4 * 4);
        float4 hv3 = *(const float4*)(h1 + (size_t)s3 * 64 + c4 * 4);
        e0 = e0 > 0.f ? e0 : NEG * e0;
        e1 = e1 > 0.f ? e1 : NEG * e1;
        e2 = e2 > 0.f ? e2 : NEG * e2;
        e3 = e3 > 0.f ? e3 : NEG * e3;
        float p0 = __expf(e0), p1 = __expf(e1), p2 = __expf(e2), p3 = __expf(e3);
        accp += (p0 + p1) + (p2 + p3);
        accv.x += p0 * hv0.x + p1 * hv1.x + p2 * hv2.x + p3 * hv3.x;
        accv.y += p0 * hv0.y + p1 * hv1.y + p2 * hv2.y + p3 * hv3.y;
        accv.z += p0 * hv0.z + p1 * hv1.z + p2 * hv2.z + p3 * hv3.z;
        accv.w += p0 * hv0.w + p1 * hv1.w + p2 * hv2.w + p3 * hv3.w;
    }
    for (; i < len; i += 4) {
        int s0 = csr[start + i];
        float e0 = as1[s0 * 8 + h] + adv;
        float4 hv0 = *(const float4*)(h1 + (size_t)s0 * 64 + c4 * 4);
        e0 = e0 > 0.f ? e0 : NEG * e0;
        float p0 = __expf(e0);
        accp += p0;
        accv.x += p0 * hv0.x;
        accv.y += p0 * hv0.y;
        accv.z += p0 * hv0.z;
        accv.w += p0 * hv0.w;
    }
    accp   += __shfl_xor(accp, 16);
    accv.x += __shfl_xor(accv.x, 16);
    accv.y += __shfl_xor(accv.y, 16);
    accv.z += __shfl_xor(accv.z, 16);
    accv.w += __shfl_xor(accv.w, 16);
    accp   += __shfl_xor(accp, 32);
    accv.x += __shfl_xor(accv.x, 32);
    accv.y += __shfl_xor(accv.y, 32);
    accv.z += __shfl_xor(accv.z, 32);
    accv.w += __shfl_xor(accv.w, 32);
    if (sub == 0) {
        float inv = 1.f / (accp + 1e-16f);
        float4 o = make_float4(accv.x * inv, accv.y * inv, accv.z * inv, accv.w * inv);
        *(float4*)(out1 + (size_t)wid * 64 + c4 * 4) = o;
    }
}

// ---------------------------------------------------------------------------
// K5: fused bias + ELU + GEMM2(64x10) + layer-2 attention dots (thread/node)
// h2 rows padded to stride 16 (one aligned 64B line per row)
// ---------------------------------------------------------------------------
__global__ void node2_k(const float* __restrict__ out1, const float* __restrict__ b1,
                        const float* __restrict__ W2, const float* __restrict__ as2w,
                        const float* __restrict__ ad2w, float* __restrict__ h2,
                        float* __restrict__ as2, float* __restrict__ ad2, int Nn)
{
    int n = blockIdx.x * 256 + threadIdx.x;
    if (n >= Nn) return;
    float g[64];
#pragma unroll
    for (int c = 0; c < 16; ++c) {
        float4 v = *(const float4*)(out1 + (size_t)n * 64 + c * 4);
        float4 b = *(const float4*)(b1 + c * 4);
        float t0 = v.x + b.x, t1 = v.y + b.y, t2 = v.z + b.z, t3 = v.w + b.w;
        g[c * 4 + 0] = t0 > 0.f ? t0 : expm1f(t0);
        g[c * 4 + 1] = t1 > 0.f ? t1 : expm1f(t1);
        g[c * 4 + 2] = t2 > 0.f ? t2 : expm1f(t2);
        g[c * 4 + 3] = t3 > 0.f ? t3 : expm1f(t3);
    }
    float acc[10] = {};
#pragma unroll
    for (int k = 0; k < 64; ++k) {
#pragma unroll
        for (int j = 0; j < 10; ++j) acc[j] += g[k] * W2[k * 10 + j];
    }
    float s = 0.f, d = 0.f;
#pragma unroll
    for (int j = 0; j < 10; ++j) {
        h2[(size_t)n * 16 + j] = acc[j];
        s += acc[j] * as2w[j];
        d += acc[j] * ad2w[j];
    }
    as2[n] = s;
    ad2[n] = d;
}

// ---------------------------------------------------------------------------
// Layer-2 fused softmax+aggregate: one wave per dst, lane = sub*16 + c,
// 4-deep unroll -> 16 edges in flight.
// ---------------------------------------------------------------------------
__global__ __launch_bounds__(256) void agg2_k(const int* __restrict__ csr,
                                              const int* __restrict__ rowptr,
                                              const float* __restrict__ as2,
                                              const float* __restrict__ ad2,
                                              const float* __restrict__ h2,
                                              float* __restrict__ out, int Nn)
{
    int wid = (blockIdx.x * 256 + threadIdx.x) >> 6;
    if (wid >= Nn) return;
    int lane = threadIdx.x & 63;
    int sub = lane >> 4;
    int c = lane & 15;
    float adv = ad2[wid];
    int start = rowptr[wid];
    int len = rowptr[wid + 1] - start;
    float accp = 0.f, accv = 0.f;
    int i = sub;
    for (; i + 12 < len; i += 16) {
        int s0 = csr[start + i];
        int s1 = csr[start + i + 4];
        int s2 = csr[start + i + 8];
        int s3 = csr[start + i + 12];
        float e0 = as2[s0] + adv;
        float e1 = as2[s1] + adv;
        float e2 = as2[s2] + adv;
        float e3 = as2[s3] + adv;
        float v0 = (c < 10) ? h2[(size_t)s0 * 16 + c] : 0.f;
        float v1 = (c < 10) ? h2[(size_t)s1 * 16 + c] : 0.f;
        float v2 = (c < 10) ? h2[(size_t)s2 * 16 + c] : 0.f;
        float v3 = (c < 10) ? h2[(size_t)s3 * 16 + c] : 0.f;
        e0 = e0 > 0.f ? e0 : NEG * e0;
        e1 = e1 > 0.f ? e1 : NEG * e1;
        e2 = e2 > 0.f ? e2 : NEG * e2;
        e3 = e3 > 0.f ? e3 : NEG * e3;
        float p0 = __expf(e0), p1 = __expf(e1), p2 = __expf(e2), p3 = __expf(e3);
        accp += (p0 + p1) + (p2 + p3);
        accv += p0 * v0 + p1 * v1 + p2 * v2 + p3 * v3;
    }
    for (; i < len; i += 4) {
        int s0 = csr[start + i];
        float e0 = as2[s0] + adv;
        float v0 = (c < 10) ? h2[(size_t)s0 * 16 + c] : 0.f;
        e0 = e0 > 0.f ? e0 : NEG * e0;
        float p0 = __expf(e0);
        accp += p0;
        accv += p0 * v0;
    }
    accp += __shfl_xor(accp, 16);
    accv += __shfl_xor(accv, 16);
    accp += __shfl_xor(accp, 32);
    accv += __shfl_xor(accv, 32);
    if (sub == 0 && c < 10)
        out[(size_t)wid * 10 + c] = accv / (accp + 1e-16f);
}

// ---------------------------------------------------------------------------
// K8: in-place bias + log_softmax on d_out (thread/node)
// ---------------------------------------------------------------------------
__global__ void lsm_k(float* __restrict__ out, const float* __restrict__ b2, int Nn)
{
    int n = blockIdx.x * 256 + threadIdx.x;
    if (n >= Nn) return;
    float z[10];
    float m = -1e30f;
#pragma unroll
    for (int j = 0; j < 10; ++j) {
        z[j] = out[(size_t)n * 10 + j] + b2[j];
        m = fmaxf(m, z[j]);
    }
    float ssum = 0.f;
#pragma unroll
    for (int j = 0; j < 10; ++j) ssum += expf(z[j] - m);
    float lse = m + logf(ssum);
#pragma unroll
    for (int j = 0; j < 10; ++j) out[(size_t)n * 10 + j] = z[j] - lse;
}

// ---------------------------------------------------------------------------
extern "C" void kernel_launch(void* const* d_in, const int* in_sizes, int n_in,
                              void* d_out, int out_size, void* d_ws, size_t ws_size,
                              hipStream_t stream)
{
    const float* x     = (const float*)d_in[0];
    const float* W1    = (const float*)d_in[1];
    const float* asrc1 = (const float*)d_in[2];
    const float* adst1 = (const float*)d_in[3];
    const float* b1    = (const float*)d_in[4];
    const float* W2    = (const float*)d_in[5];
    const float* asrc2 = (const float*)d_in[6];
    const float* adst2 = (const float*)d_in[7];
    const float* b2    = (const float*)d_in[8];
    const int*   ei    = (const int*)d_in[9];
    float* out = (float*)d_out;

    int F  = in_sizes[1] / 64;       // 512
    int Nn = in_sizes[0] / F;        // 100000
    int E  = in_sizes[9] / 2;        // 1600000
    int Ep = E + Nn;
    int nb = (Nn + 1023) / 1024;

    float* f = (float*)d_ws;
    float* h1   = f;  f += (size_t)Nn * 64;
    float* as1  = f;  f += (size_t)Nn * 8;
    float* ad1  = f;  f += (size_t)Nn * 8;
    float* h2   = f;  f += (size_t)Nn * 16;
    float* as2  = f;  f += Nn;
    float* ad2  = f;  f += Nn;
    float* out1 = f;  f += (size_t)Nn * 64;
    int* ip = (int*)f;
    int* deg    = ip;  ip += Nn;
    int* rowptr = ip;  ip += Nn + 1;
    int* bsum   = ip;  ip += 256;
    int* rank   = ip;  ip += Ep;
    int* csr    = ip;  ip += Ep;

    // CSR build (shared by both layers)
    hipMemsetAsync(deg, 0, (size_t)Nn * sizeof(int), stream);
    hist_rank_k<<<(Ep + 255) / 256, 256, 0, stream>>>(ei, E, Nn, deg, rank);
    scan_a_k<<<nb, 256, 0, stream>>>(deg, Nn, bsum);
    scan_b_k<<<1, 256, 0, stream>>>(bsum, nb);
    scan_c_k<<<nb, 256, 0, stream>>>(deg, Nn, bsum, rowptr);
    scat2_k<<<(Ep + 255) / 256, 256, 0, stream>>>(ei, E, Nn, rowptr, rank, csr);

    // Layer 1
    gemm1_k<<<(Nn + 63) / 64, 256, 0, stream>>>(x, W1, h1, Nn);
    attn1_k<<<(Nn * 8 + 255) / 256, 256, 0, stream>>>(h1, asrc1, adst1, as1, ad1, Nn);
    agg1_k<<<(Nn * 64 + 255) / 256, 256, 0, stream>>>(csr, rowptr, as1, ad1, h1, out1, Nn);

    // Layer 2
    node2_k<<<(Nn + 255) / 256, 256, 0, stream>>>(out1, b1, W2, asrc2, adst2, h2, as2, ad2, Nn);
    agg2_k<<<(Nn * 64 + 255) / 256, 256, 0, stream>>>(csr, rowptr, as2, ad2, h2, out, Nn);
    lsm_k<<<(Nn + 255) / 256, 256, 0, stream>>>(out, b2, Nn);
}

// Round 6
// 583.775 us; speedup vs baseline: 1.0403x; 1.0403x over previous
//
#include <hip/hip_runtime.h>
#include <math.h>

#define NEG 0.2f

typedef __bf16 bf16x8 __attribute__((ext_vector_type(8)));
typedef float  f32x4  __attribute__((ext_vector_type(4)));

// ---------------------------------------------------------------------------
// W1 pre-swizzle: W1[512,64] f32 -> W1b bf16 in MFMA B-fragment order.
// Slot i = (ch*4+lk)*64 + n holds 8 bf16: W1[ch*32+lk*8+j][n], j=0..7.
// ---------------------------------------------------------------------------
__global__ void w1prep_k(const float* __restrict__ W1, __bf16* __restrict__ W1b)
{
    int i = blockIdx.x * 256 + threadIdx.x;   // 0..4095
    int n = i & 63;
    int k0 = (i >> 6) * 8;                    // (ch*4+lk)*8 == ch*32+lk*8
#pragma unroll
    for (int j = 0; j < 8; ++j)
        W1b[(size_t)i * 8 + j] = (__bf16)W1[(size_t)(k0 + j) * 64 + n];
}

// ---------------------------------------------------------------------------
// K1: h1[N,64] = x[N,512] @ W1[512,64] via bf16 MFMA (16x16x32).
// No LDS, no syncthreads. Block = 4 waves x 16 rows. A-fragments loaded
// straight from x (2 dwordx4/chunk), B-fragments from the pre-swizzled
// L2-resident W1b (4 x 16B loads/chunk). 16 chunks fully unrolled ->
// deep software pipeline, latency hidden by occupancy (launch_bounds 256,4).
// ---------------------------------------------------------------------------
__global__ __launch_bounds__(256, 4) void gemm1_k(const float* __restrict__ x,
                                                  const __bf16* __restrict__ W1b,
                                                  float* __restrict__ h1, int Nn)
{
    int t = threadIdx.x;
    int wave = t >> 6, lane = t & 63;
    int lm = lane & 15, lk = lane >> 4;
    int rowa = blockIdx.x * 64 + wave * 16 + lm;          // A: m = lane&15
    const float* xrow = x + (size_t)(rowa < Nn ? rowa : 0) * 512;
    f32x4 acc[4] = {};
#pragma unroll
    for (int ch = 0; ch < 16; ++ch) {
        float4 a0 = *(const float4*)(xrow + ch * 32 + lk * 8);
        float4 a1 = *(const float4*)(xrow + ch * 32 + lk * 8 + 4);
        bf16x8 af;
        af[0] = (__bf16)a0.x; af[1] = (__bf16)a0.y;
        af[2] = (__bf16)a0.z; af[3] = (__bf16)a0.w;
        af[4] = (__bf16)a1.x; af[5] = (__bf16)a1.y;
        af[6] = (__bf16)a1.z; af[7] = (__bf16)a1.w;
#pragma unroll
        for (int nt = 0; nt < 4; ++nt) {
            bf16x8 bf = *(const bf16x8*)(W1b + ((size_t)((ch * 4 + lk) * 64) + nt * 16 + lm) * 8);
            acc[nt] = __builtin_amdgcn_mfma_f32_16x16x32_bf16(af, bf, acc[nt], 0, 0, 0);
        }
    }
    // C/D: col = lane&15, row = (lane>>4)*4 + reg (verified m89)
    int rowbase = blockIdx.x * 64 + wave * 16 + lk * 4;
#pragma unroll
    for (int nt = 0; nt < 4; ++nt) {
#pragma unroll
        for (int j = 0; j < 4; ++j) {
            int gr = rowbase + j;
            if (gr < Nn) h1[(size_t)gr * 64 + nt * 16 + lm] = acc[nt][j];
        }
    }
}

// ---------------------------------------------------------------------------
// K2: per-(node,head) attention dots for layer 1
// ---------------------------------------------------------------------------
__global__ void attn1_k(const float* __restrict__ h1, const float* __restrict__ asrc,
                        const float* __restrict__ adst, float* __restrict__ as1,
                        float* __restrict__ ad1, int Nn)
{
    int tid = blockIdx.x * 256 + threadIdx.x;
    if (tid >= Nn * 8) return;
    int n = tid >> 3, h = tid & 7;
    const float* hp = h1 + (size_t)n * 64 + h * 8;
    float s = 0.f, d = 0.f;
#pragma unroll
    for (int c = 0; c < 8; ++c) {
        float v = hp[c];
        s += v * asrc[h * 8 + c];
        d += v * adst[h * 8 + c];
    }
    as1[tid] = s;
    ad1[tid] = d;
}

// ---------------------------------------------------------------------------
// CSR build: fused histogram+rank -> 3-kernel exclusive scan -> atomic-free
// scatter.
// ---------------------------------------------------------------------------
__global__ void hist_rank_k(const int* __restrict__ ei, int E, int Nn,
                            int* __restrict__ deg, int* __restrict__ rank)
{
    int e = blockIdx.x * 256 + threadIdx.x;
    int Ep = E + Nn;
    if (e >= Ep) return;
    int d = (e < E) ? ei[E + e] : e - E;
    rank[e] = atomicAdd(&deg[d], 1);
}

__global__ void scan_a_k(const int* __restrict__ deg, int Nn, int* __restrict__ bsum)
{
    __shared__ int tmp[256];
    int t = threadIdx.x;
    int base = blockIdx.x * 1024 + t * 4;
    int s = 0;
#pragma unroll
    for (int j = 0; j < 4; ++j) { int i = base + j; if (i < Nn) s += deg[i]; }
    tmp[t] = s;
    __syncthreads();
    for (int off = 1; off < 256; off <<= 1) {
        int a = (t >= off) ? tmp[t - off] : 0;
        __syncthreads();
        tmp[t] += a;
        __syncthreads();
    }
    if (t == 255) bsum[blockIdx.x] = tmp[255];
}

__global__ void scan_b_k(int* __restrict__ bsum, int nb)
{
    __shared__ int tmp[256];
    int t = threadIdx.x;
    int v = (t < nb) ? bsum[t] : 0;
    tmp[t] = v;
    __syncthreads();
    for (int off = 1; off < 256; off <<= 1) {
        int a = (t >= off) ? tmp[t - off] : 0;
        __syncthreads();
        tmp[t] += a;
        __syncthreads();
    }
    if (t < nb) bsum[t] = tmp[t] - v;  // exclusive
}

__global__ void scan_c_k(const int* __restrict__ deg, int Nn, const int* __restrict__ boff,
                         int* __restrict__ rowptr)
{
    __shared__ int tmp[256];
    int t = threadIdx.x;
    int base = blockIdx.x * 1024 + t * 4;
    int v[4];
    int s = 0;
#pragma unroll
    for (int j = 0; j < 4; ++j) {
        int i = base + j;
        v[j] = (i < Nn) ? deg[i] : 0;
        s += v[j];
    }
    tmp[t] = s;
    __syncthreads();
    for (int off = 1; off < 256; off <<= 1) {
        int a = (t >= off) ? tmp[t - off] : 0;
        __syncthreads();
        tmp[t] += a;
        __syncthreads();
    }
    int excl = boff[blockIdx.x] + tmp[t] - s;
#pragma unroll
    for (int j = 0; j < 4; ++j) {
        int i = base + j;
        if (i < Nn) {
            rowptr[i] = excl;
            excl += v[j];
            if (i == Nn - 1) rowptr[Nn] = excl;
        }
    }
}

__global__ void scat2_k(const int* __restrict__ ei, int E, int Nn,
                        const int* __restrict__ rowptr, const int* __restrict__ rank,
                        int* __restrict__ csr)
{
    int e = blockIdx.x * 256 + threadIdx.x;
    int Ep = E + Nn;
    if (e >= Ep) return;
    int s, d;
    if (e < E) { s = ei[e]; d = ei[E + e]; } else { s = d = e - E; }
    csr[rowptr[d] + rank[e]] = s;
}

// ---------------------------------------------------------------------------
// Layer-1 fused softmax+aggregate: one wave per dst node.
// lane = sub*16 + c4 (sub = edge slot, c4 = float4 chunk of the 64-ch row).
// 4-deep unroll -> 16 edge gathers in flight per wave.
// ---------------------------------------------------------------------------
__global__ __launch_bounds__(256) void agg1_k(const int* __restrict__ csr,
                                              const int* __restrict__ rowptr,
                                              const float* __restrict__ as1,
                                              const float* __restrict__ ad1,
                                              const float* __restrict__ h1,
                                              float* __restrict__ out1, int Nn)
{
    int wid = (blockIdx.x * 256 + threadIdx.x) >> 6;
    if (wid >= Nn) return;
    int lane = threadIdx.x & 63;
    int sub = lane >> 4;
    int c4 = lane & 15;
    int h = c4 >> 1;
    float adv = ad1[wid * 8 + h];
    int start = rowptr[wid];
    int len = rowptr[wid + 1] - start;
    float accp = 0.f;
    float4 accv = make_float4(0.f, 0.f, 0.f, 0.f);
    int i = sub;
    for (; i + 12 < len; i += 16) {
        int s0 = csr[start + i];
        int s1 = csr[start + i + 4];
        int s2 = csr[start + i + 8];
        int s3 = csr[start + i + 12];
        float e0 = as1[s0 * 8 + h] + adv;
        float e1 = as1[s1 * 8 + h] + adv;
        float e2 = as1[s2 * 8 + h] + adv;
        float e3 = as1[s3 * 8 + h] + adv;
        float4 hv0 = *(const float4*)(h1 + (size_t)s0 * 64 + c4 * 4);
        float4 hv1 = *(const float4*)(h1 + (size_t)s1 * 64 + c4 * 4);
        float4 hv2 = *(const float4*)(h1 + (size_t)s2 * 64 + c4 * 4);
        float4 hv3 = *(const float4*)(h1 + (size_t)s3 * 64 + c4 * 4);
        e0 = e0 > 0.f ? e0 : NEG * e0;
        e1 = e1 > 0.f ? e1 : NEG * e1;
        e2 = e2 > 0.f ? e2 : NEG * e2;
        e3 = e3 > 0.f ? e3 : NEG * e3;
        float p0 = __expf(e0), p1 = __expf(e1), p2 = __expf(e2), p3 = __expf(e3);
        accp += (p0 + p1) + (p2 + p3);
        accv.x += p0 * hv0.x + p1 * hv1.x + p2 * hv2.x + p3 * hv3.x;
        accv.y += p0 * hv0.y + p1 * hv1.y + p2 * hv2.y + p3 * hv3.y;
        accv.z += p0 * hv0.z + p1 * hv1.z + p2 * hv2.z + p3 * hv3.z;
        accv.w += p0 * hv0.w + p1 * hv1.w + p2 * hv2.w + p3 * hv3.w;
    }
    for (; i < len; i += 4) {
        int s0 = csr[start + i];
        float e0 = as1[s0 * 8 + h] + adv;
        float4 hv0 = *(const float4*)(h1 + (size_t)s0 * 64 + c4 * 4);
        e0 = e0 > 0.f ? e0 : NEG * e0;
        float p0 = __expf(e0);
        accp += p0;
        accv.x += p0 * hv0.x;
        accv.y += p0 * hv0.y;
        accv.z += p0 * hv0.z;
        accv.w += p0 * hv0.w;
    }
    accp   += __shfl_xor(accp, 16);
    accv.x += __shfl_xor(accv.x, 16);
    accv.y += __shfl_xor(accv.y, 16);
    accv.z += __shfl_xor(accv.z, 16);
    accv.w += __shfl_xor(accv.w, 16);
    accp   += __shfl_xor(accp, 32);
    accv.x += __shfl_xor(accv.x, 32);
    accv.y += __shfl_xor(accv.y, 32);
    accv.z += __shfl_xor(accv.z, 32);
    accv.w += __shfl_xor(accv.w, 32);
    if (sub == 0) {
        float inv = 1.f / (accp + 1e-16f);
        float4 o = make_float4(accv.x * inv, accv.y * inv, accv.z * inv, accv.w * inv);
        *(float4*)(out1 + (size_t)wid * 64 + c4 * 4) = o;
    }
}

// ---------------------------------------------------------------------------
// K5: fused bias + ELU + GEMM2(64x10) + layer-2 attention dots (thread/node)
// h2 rows padded to stride 16 (one aligned 64B line per row)
// ---------------------------------------------------------------------------
__global__ void node2_k(const float* __restrict__ out1, const float* __restrict__ b1,
                        const float* __restrict__ W2, const float* __restrict__ as2w,
                        const float* __restrict__ ad2w, float* __restrict__ h2,
                        float* __restrict__ as2, float* __restrict__ ad2, int Nn)
{
    int n = blockIdx.x * 256 + threadIdx.x;
    if (n >= Nn) return;
    float g[64];
#pragma unroll
    for (int c = 0; c < 16; ++c) {
        float4 v = *(const float4*)(out1 + (size_t)n * 64 + c * 4);
        float4 b = *(const float4*)(b1 + c * 4);
        float t0 = v.x + b.x, t1 = v.y + b.y, t2 = v.z + b.z, t3 = v.w + b.w;
        g[c * 4 + 0] = t0 > 0.f ? t0 : expm1f(t0);
        g[c * 4 + 1] = t1 > 0.f ? t1 : expm1f(t1);
        g[c * 4 + 2] = t2 > 0.f ? t2 : expm1f(t2);
        g[c * 4 + 3] = t3 > 0.f ? t3 : expm1f(t3);
    }
    float acc[10] = {};
#pragma unroll
    for (int k = 0; k < 64; ++k) {
#pragma unroll
        for (int j = 0; j < 10; ++j) acc[j] += g[k] * W2[k * 10 + j];
    }
    float s = 0.f, d = 0.f;
#pragma unroll
    for (int j = 0; j < 10; ++j) {
        h2[(size_t)n * 16 + j] = acc[j];
        s += acc[j] * as2w[j];
        d += acc[j] * ad2w[j];
    }
    as2[n] = s;
    ad2[n] = d;
}

// ---------------------------------------------------------------------------
// Layer-2 fused softmax+aggregate: one wave per dst, lane = sub*16 + c,
// 4-deep unroll -> 16 edges in flight.
// ---------------------------------------------------------------------------
__global__ __launch_bounds__(256) void agg2_k(const int* __restrict__ csr,
                                              const int* __restrict__ rowptr,
                                              const float* __restrict__ as2,
                                              const float* __restrict__ ad2,
                                              const float* __restrict__ h2,
                                              float* __restrict__ out, int Nn)
{
    int wid = (blockIdx.x * 256 + threadIdx.x) >> 6;
    if (wid >= Nn) return;
    int lane = threadIdx.x & 63;
    int sub = lane >> 4;
    int c = lane & 15;
    float adv = ad2[wid];
    int start = rowptr[wid];
    int len = rowptr[wid + 1] - start;
    float accp = 0.f, accv = 0.f;
    int i = sub;
    for (; i + 12 < len; i += 16) {
        int s0 = csr[start + i];
        int s1 = csr[start + i + 4];
        int s2 = csr[start + i + 8];
        int s3 = csr[start + i + 12];
        float e0 = as2[s0] + adv;
        float e1 = as2[s1] + adv;
        float e2 = as2[s2] + adv;
        float e3 = as2[s3] + adv;
        float v0 = (c < 10) ? h2[(size_t)s0 * 16 + c] : 0.f;
        float v1 = (c < 10) ? h2[(size_t)s1 * 16 + c] : 0.f;
        float v2 = (c < 10) ? h2[(size_t)s2 * 16 + c] : 0.f;
        float v3 = (c < 10) ? h2[(size_t)s3 * 16 + c] : 0.f;
        e0 = e0 > 0.f ? e0 : NEG * e0;
        e1 = e1 > 0.f ? e1 : NEG * e1;
        e2 = e2 > 0.f ? e2 : NEG * e2;
        e3 = e3 > 0.f ? e3 : NEG * e3;
        float p0 = __expf(e0), p1 = __expf(e1), p2 = __expf(e2), p3 = __expf(e3);
        accp += (p0 + p1) + (p2 + p3);
        accv += p0 * v0 + p1 * v1 + p2 * v2 + p3 * v3;
    }
    for (; i < len; i += 4) {
        int s0 = csr[start + i];
        float e0 = as2[s0] + adv;
        float v0 = (c < 10) ? h2[(size_t)s0 * 16 + c] : 0.f;
        e0 = e0 > 0.f ? e0 : NEG * e0;
        float p0 = __expf(e0);
        accp += p0;
        accv += p0 * v0;
    }
    accp += __shfl_xor(accp, 16);
    accv += __shfl_xor(accv, 16);
    accp += __shfl_xor(accp, 32);
    accv += __shfl_xor(accv, 32);
    if (sub == 0 && c < 10)
        out[(size_t)wid * 10 + c] = accv / (accp + 1e-16f);
}

// ---------------------------------------------------------------------------
// K8: in-place bias + log_softmax on d_out (thread/node)
// ---------------------------------------------------------------------------
__global__ void lsm_k(float* __restrict__ out, const float* __restrict__ b2, int Nn)
{
    int n = blockIdx.x * 256 + threadIdx.x;
    if (n >= Nn) return;
    float z[10];
    float m = -1e30f;
#pragma unroll
    for (int j = 0; j < 10; ++j) {
        z[j] = out[(size_t)n * 10 + j] + b2[j];
        m = fmaxf(m, z[j]);
    }
    float ssum = 0.f;
#pragma unroll
    for (int j = 0; j < 10; ++j) ssum += expf(z[j] - m);
    float lse = m + logf(ssum);
#pragma unroll
    for (int j = 0; j < 10; ++j) out[(size_t)n * 10 + j] = z[j] - lse;
}

// ---------------------------------------------------------------------------
extern "C" void kernel_launch(void* const* d_in, const int* in_sizes, int n_in,
                              void* d_out, int out_size, void* d_ws, size_t ws_size,
                              hipStream_t stream)
{
    const float* x     = (const float*)d_in[0];
    const float* W1    = (const float*)d_in[1];
    const float* asrc1 = (const float*)d_in[2];
    const float* adst1 = (const float*)d_in[3];
    const float* b1    = (const float*)d_in[4];
    const float* W2    = (const float*)d_in[5];
    const float* asrc2 = (const float*)d_in[6];
    const float* adst2 = (const float*)d_in[7];
    const float* b2    = (const float*)d_in[8];
    const int*   ei    = (const int*)d_in[9];
    float* out = (float*)d_out;

    int F  = in_sizes[1] / 64;       // 512
    int Nn = in_sizes[0] / F;        // 100000
    int E  = in_sizes[9] / 2;        // 1600000
    int Ep = E + Nn;
    int nb = (Nn + 1023) / 1024;

    float* f = (float*)d_ws;
    __bf16* w1b = (__bf16*)f;  f += 512 * 64 / 2;   // 64KB, 16B-aligned
    float* h1   = f;  f += (size_t)Nn * 64;
    float* as1  = f;  f += (size_t)Nn * 8;
    float* ad1  = f;  f += (size_t)Nn * 8;
    float* h2   = f;  f += (size_t)Nn * 16;
    float* as2  = f;  f += Nn;
    float* ad2  = f;  f += Nn;
    float* out1 = f;  f += (size_t)Nn * 64;
    int* ip = (int*)f;
    int* deg    = ip;  ip += Nn;
    int* rowptr = ip;  ip += Nn + 1;
    int* bsum   = ip;  ip += 256;
    int* rank   = ip;  ip += Ep;
    int* csr    = ip;  ip += Ep;

    // CSR build (shared by both layers)
    hipMemsetAsync(deg, 0, (size_t)Nn * sizeof(int), stream);
    hist_rank_k<<<(Ep + 255) / 256, 256, 0, stream>>>(ei, E, Nn, deg, rank);
    scan_a_k<<<nb, 256, 0, stream>>>(deg, Nn, bsum);
    scan_b_k<<<1, 256, 0, stream>>>(bsum, nb);
    scan_c_k<<<nb, 256, 0, stream>>>(deg, Nn, bsum, rowptr);
    scat2_k<<<(Ep + 255) / 256, 256, 0, stream>>>(ei, E, Nn, rowptr, rank, csr);

    // Layer 1
    w1prep_k<<<16, 256, 0, stream>>>(W1, w1b);
    gemm1_k<<<(Nn + 63) / 64, 256, 0, stream>>>(x, w1b, h1, Nn);
    attn1_k<<<(Nn * 8 + 255) / 256, 256, 0, stream>>>(h1, asrc1, adst1, as1, ad1, Nn);
    agg1_k<<<(Nn * 64 + 255) / 256, 256, 0, stream>>>(csr, rowptr, as1, ad1, h1, out1, Nn);

    // Layer 2
    node2_k<<<(Nn + 255) / 256, 256, 0, stream>>>(out1, b1, W2, asrc2, adst2, h2, as2, ad2, Nn);
    agg2_k<<<(Nn * 64 + 255) / 256, 256, 0, stream>>>(csr, rowptr, as2, ad2, h2, out, Nn);
    lsm_k<<<(Nn + 255) / 256, 256, 0, stream>>>(out, b2, Nn);
}